// Round 2
// baseline (30.546 us; speedup 1.0000x reference)
//
#include <hip/hip_runtime.h>
#include <math.h>
#include <stdint.h>

// MMCE: sum_{i,j} v_i v_j exp(-|p_i - p_j| / 0.4) / N^2
//   p_i = max softmax prob of row i, v_i = (argmax_i == target_i) - p_i.
//
// Decomposition: a_i = v_i e^{-p_i/bw}, b_i = v_i e^{+p_i/bw}.
//   x = a_i*b_j = v_i v_j e^{-(p_i-p_j)/bw},  y = b_i*a_j = v_i v_j e^{+(p_i-p_j)/bw}
// x and y always share sign (= sign of v_i v_j), and the desired term is
//   v_i v_j e^{-|p_i-p_j|/bw} = min(x,y) if positive, max(x,y) if negative
//   = med3(x, y, 0)  -- branch-free, 4 VALU/pair, exact at ties & diagonal.

#define WAVE 64
static constexpr float KBW_INV = 2.5f;  // 1/0.4

// ---------------- Kernel 1: per-row softmax-max stats (1 wave per row) ----
// Also zeroes the pairwise accumulator/counter (stream-ordered before K2).
__global__ __launch_bounds__(256) void rowstats_kernel(
    const float* __restrict__ inp, const int* __restrict__ tgt,
    float2* __restrict__ AB, unsigned long long* __restrict__ acc,
    unsigned int* __restrict__ counter, int N, int C) {
  if (blockIdx.x == 0 && threadIdx.x == 0) { *acc = 0ull; *counter = 0u; }
  const int wave = threadIdx.x >> 6;
  const int lane = threadIdx.x & 63;
  const int row = blockIdx.x * 4 + wave;
  if (row >= N) return;
  const int C4 = C >> 2;  // C == 1000 -> 250 float4 per row
  const float4* rp = reinterpret_cast<const float4*>(inp + (size_t)row * C);

  float4 x[4];
  bool valid[4];
  float m = -INFINITY;
  int am = 0x7fffffff;
  #pragma unroll
  for (int w = 0; w < 4; ++w) {
    const int k = lane + w * WAVE;
    valid[w] = (k < C4);
    if (valid[w]) {
      float4 v = rp[k];
      x[w] = v;
      const int base = k * 4;
      if (v.x > m) { m = v.x; am = base + 0; }
      if (v.y > m) { m = v.y; am = base + 1; }
      if (v.z > m) { m = v.z; am = base + 2; }
      if (v.w > m) { m = v.w; am = base + 3; }
    }
  }
  #pragma unroll
  for (int off = 32; off; off >>= 1) {
    float om = __shfl_xor(m, off);
    int oi = __shfl_xor(am, off);
    if (om > m || (om == m && oi < am)) { m = om; am = oi; }
  }
  float s = 0.f;
  #pragma unroll
  for (int w = 0; w < 4; ++w) {
    if (valid[w]) {
      s += __expf(x[w].x - m) + __expf(x[w].y - m) +
           __expf(x[w].z - m) + __expf(x[w].w - m);
    }
  }
  #pragma unroll
  for (int off = 32; off; off >>= 1) s += __shfl_xor(s, off);

  if (lane == 0) {
    const float p = 1.0f / s;
    const float v = ((tgt[row] == am) ? 1.0f : 0.0f) - p;
    float2 ab;
    ab.x = v * __expf(-p * KBW_INV);  // a_i
    ab.y = v * __expf(p * KBW_INV);   // b_i
    AB[row] = ab;
  }
}

// ---------------- Kernel 2: pairwise sum, fused final reduction -----------
#define IPT 4      // i-rows per thread
#define JBLK 128   // j-rows staged per block
// grid = (N/(256*IPT)) * (N/JBLK) = 8 * 64 = 512 blocks

static constexpr double FXSCALE = 1073741824.0;  // 2^30

__global__ __launch_bounds__(256) void pairwise_kernel(
    const float2* __restrict__ AB, unsigned long long* __restrict__ acc,
    unsigned int* __restrict__ counter, float* __restrict__ out, int N,
    int nBlocks) {
  __shared__ float2 sj[JBLK];
  const int nJB = N / JBLK;
  const int bi = blockIdx.x / nJB;
  const int bj = blockIdx.x % nJB;
  const int tid = threadIdx.x;

  if (tid < JBLK) sj[tid] = AB[bj * JBLK + tid];

  float2 abi[IPT];
  #pragma unroll
  for (int u = 0; u < IPT; ++u) abi[u] = AB[bi * (256 * IPT) + u * 256 + tid];
  __syncthreads();

  float facc[IPT];
  #pragma unroll
  for (int u = 0; u < IPT; ++u) facc[u] = 0.f;

  #pragma unroll 8
  for (int t = 0; t < JBLK; ++t) {
    const float aj = sj[t].x;   // uniform t -> LDS broadcast, conflict-free
    const float bj_ = sj[t].y;
    #pragma unroll
    for (int u = 0; u < IPT; ++u) {
      const float xx = abi[u].x * bj_;  // a_i * b_j
      const float yy = abi[u].y * aj;   // b_i * a_j
      facc[u] += __builtin_amdgcn_fmed3f(xx, yy, 0.0f);
    }
  }

  double dacc = (double)((facc[0] + facc[1]) + (facc[2] + facc[3]));
  #pragma unroll
  for (int off = 32; off; off >>= 1) dacc += __shfl_xor(dacc, off);
  __shared__ double wsum[4];
  if ((tid & 63) == 0) wsum[tid >> 6] = dacc;
  __syncthreads();
  if (tid == 0) {
    const double blocksum = (wsum[0] + wsum[1]) + (wsum[2] + wsum[3]);
    const long long fx = __double2ll_rn(blocksum * FXSCALE);
    atomicAdd(acc, (unsigned long long)fx);  // integer adds commute: deterministic
    __threadfence();
    const unsigned int done = atomicAdd(counter, 1u);
    if (done == (unsigned int)nBlocks - 1u) {
      const unsigned long long total = atomicAdd(acc, 0ull);
      const double s = (double)(long long)total * (1.0 / FXSCALE);
      out[0] = (float)(s / ((double)N * (double)N));
    }
  }
}

extern "C" void kernel_launch(void* const* d_in, const int* in_sizes, int n_in,
                              void* d_out, int out_size, void* d_ws, size_t ws_size,
                              hipStream_t stream) {
  const float* inp = (const float*)d_in[0];
  const int* tgt = (const int*)d_in[1];
  const int N = in_sizes[1];             // 8192
  const int C = in_sizes[0] / N;         // 1000

  float2* AB = (float2*)d_ws;                                  // N float2
  unsigned long long* acc =
      (unsigned long long*)(((uintptr_t)(AB + N) + 15) & ~(uintptr_t)15);
  unsigned int* counter = (unsigned int*)(acc + 1);

  const int rowBlocks = (N + 3) / 4;     // 4 waves/block, 1 row/wave
  rowstats_kernel<<<rowBlocks, 256, 0, stream>>>(inp, tgt, AB, acc, counter, N, C);

  const int nIB = N / (256 * IPT);       // 8
  const int nJB = N / JBLK;              // 64
  const int nPair = nIB * nJB;           // 512 blocks
  pairwise_kernel<<<nPair, 256, 0, stream>>>(AB, acc, counter, (float*)d_out,
                                             N, nPair);
}